// Round 6
// baseline (259.292 us; speedup 1.0000x reference)
//
#include <hip/hip_runtime.h>

typedef unsigned short u16;
typedef unsigned int u32;
typedef __attribute__((ext_vector_type(8))) short short8;
typedef __attribute__((ext_vector_type(8))) _Float16 half8;
typedef __attribute__((ext_vector_type(4))) float f32x4;
typedef __attribute__((ext_vector_type(16))) float f32x16;
typedef __attribute__((ext_vector_type(4))) u32 u32x4;

#define S_LEN 2048
#define EDIM  1024
#define DK    64
#define NHEAD 16
// softmax scale 1/8 folded with log2(e) into the Q projection:
#define QSCALE 0.1803368801111f

__device__ inline u16 f2bf(float f) {
    u32 u = __builtin_bit_cast(u32, f);
    u += 0x7fffu + ((u >> 16) & 1u);   // RNE
    return (u16)(u >> 16);
}
__device__ inline u16 f2h(float f) {   // fp32 -> fp16 bits (RNE)
    _Float16 h = (_Float16)f;
    return __builtin_bit_cast(u16, h);
}

#define ASYNC16(gp, lp)                                                        \
    __builtin_amdgcn_global_load_lds(                                          \
        (const __attribute__((address_space(1))) u32*)(gp),                    \
        (__attribute__((address_space(3))) u32*)(lp), 16, 0, 0)

// ---------------------------------------------------------------------------
// Fused fp32->bf16 converts: segment 0 = x (4M els), 1..3 = Wq/Wk/Wv (1M each)
// ---------------------------------------------------------------------------
__global__ __launch_bounds__(256)
void conv_all(const float* __restrict__ x,  const float* __restrict__ Wq,
              const float* __restrict__ Wk, const float* __restrict__ Wv,
              u16* __restrict__ xb, u16* __restrict__ Wb /*3M contiguous*/) {
    const int blk = blockIdx.x;
    const float* src; u16* dst; int idx;
    if (blk < 4096)      { src = x;  dst = xb;             idx = blk; }
    else if (blk < 5120) { src = Wq; dst = Wb;             idx = blk - 4096; }
    else if (blk < 6144) { src = Wk; dst = Wb + (1 << 20); idx = blk - 5120; }
    else                 { src = Wv; dst = Wb + (2 << 20); idx = blk - 6144; }
    const int i = idx * 1024 + threadIdx.x * 4;
    const float4 v = *(const float4*)(src + i);
    u16 o[4] = { f2bf(v.x), f2bf(v.y), f2bf(v.z), f2bf(v.w) };
    *(ulong1*)(dst + i) = *(ulong1*)o;
}

__global__ __launch_bounds__(256)
void f32_to_bf16(const float* __restrict__ src, u16* __restrict__ dst, int n) {
    const int i = (blockIdx.x * 256 + threadIdx.x) * 4;
    if (i + 3 < n) {
        const float4 v = *(const float4*)(src + i);
        u16 o[4] = { f2bf(v.x), f2bf(v.y), f2bf(v.z), f2bf(v.w) };
        *(ulong1*)(dst + i) = *(ulong1*)o;
    }
}

// ---------------------------------------------------------------------------
// NT GEMM: C[m][n] = sum_k A[m][k]*B[n][k]. Block tile (MT*32) x 128, BK=32,
// global_load_lds(16B), 4 waves (2x2), per-wave MTx4 16x16x32 MFMAs.
// EPI 0 (QKV fused, z selects): z0 -> Q bf16 * QSCALE, z1 -> K bf16,
//   z2 -> V scattered to VT[(b*16+h)*64+d][s] as FP16.   EPI 2: fp32.
// BF32: B is fp32 in global, staged fp32, converted at fragment read.
// ---------------------------------------------------------------------------
template<int EPI, bool BF32, int MT>
__global__ __launch_bounds__(256, 2)
void gemm128(const u16* __restrict__ A,
             const void* __restrict__ B0, const void* __restrict__ B1,
             const void* __restrict__ B2,
             u16* __restrict__ C0, u16* __restrict__ C1, u16* __restrict__ C2,
             float* __restrict__ Cf, int M, int N, int K) {
    const void* Bv = B0;
    u16*        Cp = C0;
    float       cscale = (EPI == 0) ? QSCALE : 1.0f;
    if (blockIdx.z == 1) { Bv = B1; Cp = C1; cscale = 1.0f; }
    else if (blockIdx.z == 2) { Bv = B2; Cp = C2; cscale = 1.0f; }

    const int tid  = threadIdx.x;
    const int lane = tid & 63;
    const int w    = tid >> 6;
    const int quad = lane >> 4;
    const int l16  = lane & 15;
    const int wm   = w >> 1;
    const int wn   = w & 1;
    const int m0   = blockIdx.y * (MT * 32);
    const int n0   = blockIdx.x * 128;

    __shared__ u16 lA[MT * 32 * 32];
    __shared__ __align__(16) char lBraw[BF32 ? 128 * 32 * 4 : 128 * 32 * 2];

    f32x4 acc[MT][4] = {};

    for (int k0 = 0; k0 < K; k0 += 32) {
        __syncthreads();
#pragma unroll
        for (int i = 0; i < MT / 2; ++i) {
            const int row = w * (MT * 8) + i * 16 + (lane >> 2);
            const int col = (lane & 3) * 8;
            ASYNC16(A + (size_t)(m0 + row) * K + k0 + col,
                    &lA[(w * (MT * 8) + i * 16) * 32]);
        }
        if (BF32) {
            const float* Bp = (const float*)Bv;
            float*       lB = (float*)lBraw;
#pragma unroll
            for (int i = 0; i < 4; ++i) {
                const int row = w * 32 + i * 8 + (lane >> 3);
                const int col = (lane & 7) * 4;
                ASYNC16(Bp + (size_t)(n0 + row) * K + k0 + col,
                        &lB[(w * 32 + i * 8) * 32]);
            }
        } else {
            const u16* Bp = (const u16*)Bv;
            u16*       lB = (u16*)lBraw;
#pragma unroll
            for (int i = 0; i < 2; ++i) {
                const int row = w * 32 + i * 16 + (lane >> 2);
                const int col = (lane & 3) * 8;
                ASYNC16(Bp + (size_t)(n0 + row) * K + k0 + col,
                        &lB[(w * 32 + i * 16) * 32]);
            }
        }
        __syncthreads();

        short8 av[MT], bv[4];
#pragma unroll
        for (int t = 0; t < MT; ++t)
            av[t] = *(const short8*)&lA[(wm * (MT * 16) + t * 16 + l16) * 32 + quad * 8];
        if (BF32) {
            const float* lB = (const float*)lBraw;
#pragma unroll
            for (int t = 0; t < 4; ++t) {
                const float* src = &lB[(wn * 64 + t * 16 + l16) * 32 + quad * 8];
                const f32x4 x0 = *(const f32x4*)src;
                const f32x4 x1 = *(const f32x4*)(src + 4);
                short8 bq;
#pragma unroll
                for (int j = 0; j < 4; ++j) {
                    bq[j]     = (short)f2bf(x0[j]);
                    bq[4 + j] = (short)f2bf(x1[j]);
                }
                bv[t] = bq;
            }
        } else {
            const u16* lB = (const u16*)lBraw;
#pragma unroll
            for (int t = 0; t < 4; ++t)
                bv[t] = *(const short8*)&lB[(wn * 64 + t * 16 + l16) * 32 + quad * 8];
        }

#pragma unroll
        for (int mt = 0; mt < MT; ++mt)
#pragma unroll
            for (int nt = 0; nt < 4; ++nt)
                acc[mt][nt] = __builtin_amdgcn_mfma_f32_16x16x32_bf16(
                    av[mt], bv[nt], acc[mt][nt], 0, 0, 0);
    }

    // epilogue: C/D layout col=lane&15, row=quad*4+reg
#pragma unroll
    for (int mt = 0; mt < MT; ++mt)
#pragma unroll
        for (int nt = 0; nt < 4; ++nt) {
            if (EPI == 0 && blockIdx.z == 2) {
                const int col  = n0 + wn * 64 + nt * 16 + l16;
                const int h    = (col >> 6) & 15;
                const int d    = col & 63;
                const int rowb = m0 + wm * (MT * 16) + mt * 16 + quad * 4;
                const int b    = rowb >> 11;
                const int s    = rowb & 2047;
                ushort4 o;   // V stored as FP16 for the f16 PV MFMA
                o.x = f2h(acc[mt][nt][0]);
                o.y = f2h(acc[mt][nt][1]);
                o.z = f2h(acc[mt][nt][2]);
                o.w = f2h(acc[mt][nt][3]);
                *(ushort4*)&Cp[((size_t)(b * 16 + h) * 64 + d) * S_LEN + s] = o;
            } else {
#pragma unroll
                for (int r = 0; r < 4; ++r) {
                    const int row = m0 + wm * (MT * 16) + mt * 16 + quad * 4 + r;
                    const int col = n0 + wn * 64 + nt * 16 + l16;
                    if (EPI == 2)
                        Cf[(size_t)row * N + col] = acc[mt][nt][r];
                    else
                        Cp[(size_t)row * N + col] = f2bf(acc[mt][nt][r] * cscale);
                }
            }
        }
}

// ---------------------------------------------------------------------------
// Attention v4: barrier-free. Block = (bh, 128-q-tile); wave owns 32 q-rows,
// iterates all j in 32-tiles. K and V^T fragments are loaded DIRECTLY from
// global into MFMA operand registers (per-lane dwordx4) — no LDS, no
// __syncthreads, so global latency is hidden by pipelined loads (aK
// prefetched one tile ahead, bV issued before the softmax VALU section) and
// cross-wave overlap. Grid x = bh so XCD round-robin keeps each head's
// K/V (512 KB) resident in one XCD's L2.
// Unstabilized exp2 softmax (scale folded into Q at projection time);
// P packed to fp16 via cvt_pkrtz; PV via f16 MFMA.
// ---------------------------------------------------------------------------
__global__ __launch_bounds__(256)
void attn4(const u16* __restrict__ Qg, const u16* __restrict__ Kg,
           const u16* __restrict__ VTg /*fp16*/, const float* __restrict__ qp,
           u16* __restrict__ Mg) {
    const int tid  = threadIdx.x;
    const int lane = tid & 63;
    const int w    = tid >> 6;
    const int l32  = lane & 31;
    const int hi   = lane >> 5;
    const int bh   = blockIdx.x;
    const int b    = bh >> 4;
    const int h    = bh & 15;
    const int q0   = blockIdx.y * 128;

    const float qc = cosf(qp[0] + qp[1]);

    // Q as MFMA B-operand: lane = m = q0 + w*32 + l32, k = kk*16 + hi*8 + i
    short8 bq[4];
    {
        const u16* qrow = Qg + (size_t)(b * S_LEN + q0 + w * 32 + l32) * EDIM +
                          h * DK + hi * 8;
#pragma unroll
        for (int kk = 0; kk < 4; ++kk)
            bq[kk] = *(const short8*)(qrow + kk * 16);
    }

    // K fragment base: lane = j = j0 + l32, 16B piece kk*16 + hi*8
    const u16* kbase = Kg + (size_t)(b * S_LEN + l32) * EDIM + h * DK + hi * 8;
    // V^T fragment base: lane = d = dt*32 + l32, 16B piece at j + s*16 + hi*8
    const u16* vbase = VTg + ((size_t)(bh * DK + l32) * S_LEN) + hi * 8;

    f32x16 oacc[2] = {};   // lane = d = dt*32+l32, regs = m (C layout)
    float  li = 0.f;

    short8 aKc[4];
#pragma unroll
    for (int kk = 0; kk < 4; ++kk)
        aKc[kk] = *(const short8*)(kbase + kk * 16);

    for (int j0 = 0; j0 < S_LEN; j0 += 32) {
        // prefetch next K tile (last iter: redundant reload of current)
        const int jn = (j0 + 32 < S_LEN) ? (j0 + 32) : j0;
        short8 aKn[4];
#pragma unroll
        for (int kk = 0; kk < 4; ++kk)
            aKn[kk] = *(const short8*)(kbase + (size_t)jn * EDIM + kk * 16);

        // V fragments for the current tile (issued early; consumed after VALU)
        half8 bV[2][2];
#pragma unroll
        for (int s = 0; s < 2; ++s)
#pragma unroll
            for (int dt = 0; dt < 2; ++dt)
                bV[s][dt] = *(const half8*)
                    (vbase + (size_t)(dt * 32) * S_LEN + j0 + s * 16);

        // S^T tile: D[j][m], lane = m, regs = j
        f32x16 sT = {};
#pragma unroll
        for (int kk = 0; kk < 4; ++kk)
            sT = __builtin_amdgcn_mfma_f32_32x32x16_bf16(aKc[kk], bq[kk], sT, 0, 0, 0);

        float e[16];
#pragma unroll
        for (int r = 0; r < 16; ++r) {
            e[r] = __builtin_amdgcn_exp2f(sT[r]);
            li += e[r];
        }
#pragma unroll
        for (int s = 0; s < 2; ++s) {
            const u32 P0 = __builtin_bit_cast(u32,
                __builtin_amdgcn_cvt_pkrtz(e[8 * s + 0], e[8 * s + 1]));
            const u32 P1 = __builtin_bit_cast(u32,
                __builtin_amdgcn_cvt_pkrtz(e[8 * s + 2], e[8 * s + 3]));
            const u32 P2 = __builtin_bit_cast(u32,
                __builtin_amdgcn_cvt_pkrtz(e[8 * s + 4], e[8 * s + 5]));
            const u32 P3 = __builtin_bit_cast(u32,
                __builtin_amdgcn_cvt_pkrtz(e[8 * s + 6], e[8 * s + 7]));
            const u32 XA = (u32)__shfl_xor((int)(hi ? P0 : P2), 32, 64);
            const u32 XB = (u32)__shfl_xor((int)(hi ? P1 : P3), 32, 64);
            u32x4 t;
            t[0] = hi ? XA : P0;
            t[1] = hi ? XB : P1;
            t[2] = hi ? P2 : XA;
            t[3] = hi ? P3 : XB;
            const half8 aP = __builtin_bit_cast(half8, t);
#pragma unroll
            for (int dt = 0; dt < 2; ++dt)
                oacc[dt] = __builtin_amdgcn_mfma_f32_32x32x16_f16(
                    aP, bV[s][dt], oacc[dt], 0, 0, 0);
        }

#pragma unroll
        for (int kk = 0; kk < 4; ++kk)
            aKc[kk] = aKn[kk];
    }

    // epilogue: li (lane = m) -> merge hi halves; normalize oacc (regs = m)
    li += __shfl_xor(li, 32, 64);
    const float inv = 1.f / li;
#pragma unroll
    for (int r = 0; r < 16; ++r) {
        const int ml   = (r & 3) + 8 * (r >> 2) + 4 * hi;
        const float im = __shfl(inv, ml, 64);
        const int sg   = q0 + w * 32 + ml;
#pragma unroll
        for (int dt = 0; dt < 2; ++dt) {
            const int d = dt * 32 + l32;
            float val = oacc[dt][r] * im;
            if (d < 4) val += qc;
            Mg[(size_t)(b * S_LEN + sg) * EDIM + h * DK + d] = f2bf(val);
        }
    }
}

// ---------------------------------------------------------------------------
// Workspace: fast path (ws >= 22 MB): xb[0,8M) + VT[8M,16M) + Wqkv[16M,22M);
//   Wo converted into the Wq slot after the QKV GEMM (stream-ordered).
// tight path (ws >= 16 MB): xb + VT only; weights read fp32 inside the GEMM.
// Q,K (bf16, 8 MB each) live in d_out (16 MB fp32), dead before the final
// projection overwrites it.  Host branch depends only on ws_size (constant).
// ---------------------------------------------------------------------------
extern "C" void kernel_launch(void* const* d_in, const int* in_sizes, int n_in,
                              void* d_out, int out_size, void* d_ws, size_t ws_size,
                              hipStream_t stream) {
    const float* x  = (const float*)d_in[0];
    const float* Wq = (const float*)d_in[1];
    const float* Wk = (const float*)d_in[2];
    const float* Wv = (const float*)d_in[3];
    const float* Wo = (const float*)d_in[4];
    const float* qp = (const float*)d_in[5];

    const size_t BUF  = (size_t)2 * S_LEN * EDIM;   // 4M elements
    const size_t WBUF = (size_t)EDIM * EDIM;        // 1M elements

    u16* Q  = (u16*)d_out;
    u16* Kb = Q + BUF;

    u16* ws    = (u16*)d_ws;
    u16* xb    = ws;                 // dead after QKV; mixed reuses it
    u16* mixed = xb;
    u16* VT    = ws + BUF;           // fp16 V^T
    u16* Wqb   = ws + 2 * BUF;       // fast path only: Wq,Wk,Wv contiguous
    u16* Wkb   = Wqb + WBUF;
    u16* Wvb   = Wkb + WBUF;
    u16* Wob   = Wqb;                // reuses Wq slot after QKV GEMM
    float* out = (float*)d_out;

    const int M = 2 * S_LEN, N = EDIM, Kd = EDIM;
    const dim3 gqkv(N / 128, M / 128, 3);
    const dim3 gfin(N / 128, M / 64, 1);            // 64-row tiles: 512 blocks
    const dim3 gattn(2 * NHEAD, S_LEN / 128, 1);    // x = bh for XCD locality
    const bool fast = ws_size >= (size_t)(2 * BUF + 3 * WBUF) * sizeof(u16);

    if (fast) {
        conv_all<<<7168, 256, 0, stream>>>(x, Wq, Wk, Wv, xb, Wqb);
        gemm128<0, false, 4><<<gqkv, 256, 0, stream>>>(
            xb, Wqb, Wkb, Wvb, Q, Kb, VT, nullptr, M, N, Kd);
        f32_to_bf16<<<(int)(WBUF / 1024), 256, 0, stream>>>(Wo, Wob, (int)WBUF);
        attn4<<<gattn, 256, 0, stream>>>(Q, Kb, VT, qp, mixed);
        gemm128<2, false, 2><<<gfin, 256, 0, stream>>>(
            mixed, Wob, Wob, Wob, nullptr, nullptr, nullptr, out, M, N, Kd);
    } else {
        f32_to_bf16<<<(int)(BUF / 1024), 256, 0, stream>>>(x, xb, (int)BUF);
        gemm128<0, true, 4><<<gqkv, 256, 0, stream>>>(
            xb, Wq, Wk, Wv, Q, Kb, VT, nullptr, M, N, Kd);
        attn4<<<gattn, 256, 0, stream>>>(Q, Kb, VT, qp, mixed);
        gemm128<2, true, 2><<<gfin, 256, 0, stream>>>(
            mixed, Wo, Wo, Wo, nullptr, nullptr, nullptr, out, M, N, Kd);
    }
}

// Round 7
// 187.365 us; speedup vs baseline: 1.3839x; 1.3839x over previous
//
#include <hip/hip_runtime.h>

typedef unsigned short u16;
typedef unsigned int u32;
typedef __attribute__((ext_vector_type(8))) short short8;
typedef __attribute__((ext_vector_type(8))) _Float16 half8;
typedef __attribute__((ext_vector_type(4))) float f32x4;
typedef __attribute__((ext_vector_type(16))) float f32x16;
typedef __attribute__((ext_vector_type(4))) u32 u32x4;

#define S_LEN 2048
#define EDIM  1024
#define DK    64
#define NHEAD 16
// softmax scale 1/8 folded with log2(e) into the Q projection:
#define QSCALE 0.1803368801111f

__device__ inline u16 f2bf(float f) {
    u32 u = __builtin_bit_cast(u32, f);
    u += 0x7fffu + ((u >> 16) & 1u);   // RNE
    return (u16)(u >> 16);
}
__device__ inline u16 f2h(float f) {   // fp32 -> fp16 bits (RNE)
    _Float16 h = (_Float16)f;
    return __builtin_bit_cast(u16, h);
}

#define ASYNC16(gp, lp)                                                        \
    __builtin_amdgcn_global_load_lds(                                          \
        (const __attribute__((address_space(1))) u32*)(gp),                    \
        (__attribute__((address_space(3))) u32*)(lp), 16, 0, 0)

// ---------------------------------------------------------------------------
// Fused fp32->bf16 converts: segment 0 = x (4M els), 1..3 = Wq/Wk/Wv (1M each)
// ---------------------------------------------------------------------------
__global__ __launch_bounds__(256)
void conv_all(const float* __restrict__ x,  const float* __restrict__ Wq,
              const float* __restrict__ Wk, const float* __restrict__ Wv,
              u16* __restrict__ xb, u16* __restrict__ Wb /*3M contiguous*/) {
    const int blk = blockIdx.x;
    const float* src; u16* dst; int idx;
    if (blk < 4096)      { src = x;  dst = xb;             idx = blk; }
    else if (blk < 5120) { src = Wq; dst = Wb;             idx = blk - 4096; }
    else if (blk < 6144) { src = Wk; dst = Wb + (1 << 20); idx = blk - 5120; }
    else                 { src = Wv; dst = Wb + (2 << 20); idx = blk - 6144; }
    const int i = idx * 1024 + threadIdx.x * 4;
    const float4 v = *(const float4*)(src + i);
    u16 o[4] = { f2bf(v.x), f2bf(v.y), f2bf(v.z), f2bf(v.w) };
    *(ulong1*)(dst + i) = *(ulong1*)o;
}

__global__ __launch_bounds__(256)
void f32_to_bf16(const float* __restrict__ src, u16* __restrict__ dst, int n) {
    const int i = (blockIdx.x * 256 + threadIdx.x) * 4;
    if (i + 3 < n) {
        const float4 v = *(const float4*)(src + i);
        u16 o[4] = { f2bf(v.x), f2bf(v.y), f2bf(v.z), f2bf(v.w) };
        *(ulong1*)(dst + i) = *(ulong1*)o;
    }
}

// ---------------------------------------------------------------------------
// NT GEMM: C[m][n] = sum_k A[m][k]*B[n][k]. Block tile (MT*32) x 128, BK=32,
// global_load_lds(16B), 4 waves (2x2), per-wave MTx4 16x16x32 MFMAs.
// EPI 0 (QKV fused, z selects): z0 -> Q bf16 * QSCALE, z1 -> K bf16,
//   z2 -> V scattered to VT[(b*16+h)*64+d][s] as FP16.   EPI 2: fp32.
// BF32: B is fp32 in global, staged fp32, converted at fragment read.
// ---------------------------------------------------------------------------
template<int EPI, bool BF32, int MT>
__global__ __launch_bounds__(256, 2)
void gemm128(const u16* __restrict__ A,
             const void* __restrict__ B0, const void* __restrict__ B1,
             const void* __restrict__ B2,
             u16* __restrict__ C0, u16* __restrict__ C1, u16* __restrict__ C2,
             float* __restrict__ Cf, int M, int N, int K) {
    const void* Bv = B0;
    u16*        Cp = C0;
    float       cscale = (EPI == 0) ? QSCALE : 1.0f;
    if (blockIdx.z == 1) { Bv = B1; Cp = C1; cscale = 1.0f; }
    else if (blockIdx.z == 2) { Bv = B2; Cp = C2; cscale = 1.0f; }

    const int tid  = threadIdx.x;
    const int lane = tid & 63;
    const int w    = tid >> 6;
    const int quad = lane >> 4;
    const int l16  = lane & 15;
    const int wm   = w >> 1;
    const int wn   = w & 1;
    const int m0   = blockIdx.y * (MT * 32);
    const int n0   = blockIdx.x * 128;

    __shared__ u16 lA[MT * 32 * 32];
    __shared__ __align__(16) char lBraw[BF32 ? 128 * 32 * 4 : 128 * 32 * 2];

    f32x4 acc[MT][4] = {};

    for (int k0 = 0; k0 < K; k0 += 32) {
        __syncthreads();
#pragma unroll
        for (int i = 0; i < MT / 2; ++i) {
            const int row = w * (MT * 8) + i * 16 + (lane >> 2);
            const int col = (lane & 3) * 8;
            ASYNC16(A + (size_t)(m0 + row) * K + k0 + col,
                    &lA[(w * (MT * 8) + i * 16) * 32]);
        }
        if (BF32) {
            const float* Bp = (const float*)Bv;
            float*       lB = (float*)lBraw;
#pragma unroll
            for (int i = 0; i < 4; ++i) {
                const int row = w * 32 + i * 8 + (lane >> 3);
                const int col = (lane & 7) * 4;
                ASYNC16(Bp + (size_t)(n0 + row) * K + k0 + col,
                        &lB[(w * 32 + i * 8) * 32]);
            }
        } else {
            const u16* Bp = (const u16*)Bv;
            u16*       lB = (u16*)lBraw;
#pragma unroll
            for (int i = 0; i < 2; ++i) {
                const int row = w * 32 + i * 16 + (lane >> 2);
                const int col = (lane & 3) * 8;
                ASYNC16(Bp + (size_t)(n0 + row) * K + k0 + col,
                        &lB[(w * 32 + i * 16) * 32]);
            }
        }
        __syncthreads();

        short8 av[MT], bv[4];
#pragma unroll
        for (int t = 0; t < MT; ++t)
            av[t] = *(const short8*)&lA[(wm * (MT * 16) + t * 16 + l16) * 32 + quad * 8];
        if (BF32) {
            const float* lB = (const float*)lBraw;
#pragma unroll
            for (int t = 0; t < 4; ++t) {
                const float* src = &lB[(wn * 64 + t * 16 + l16) * 32 + quad * 8];
                const f32x4 x0 = *(const f32x4*)src;
                const f32x4 x1 = *(const f32x4*)(src + 4);
                short8 bq;
#pragma unroll
                for (int j = 0; j < 4; ++j) {
                    bq[j]     = (short)f2bf(x0[j]);
                    bq[4 + j] = (short)f2bf(x1[j]);
                }
                bv[t] = bq;
            }
        } else {
            const u16* lB = (const u16*)lBraw;
#pragma unroll
            for (int t = 0; t < 4; ++t)
                bv[t] = *(const short8*)&lB[(wn * 64 + t * 16 + l16) * 32 + quad * 8];
        }

#pragma unroll
        for (int mt = 0; mt < MT; ++mt)
#pragma unroll
            for (int nt = 0; nt < 4; ++nt)
                acc[mt][nt] = __builtin_amdgcn_mfma_f32_16x16x32_bf16(
                    av[mt], bv[nt], acc[mt][nt], 0, 0, 0);
    }

    // epilogue: C/D layout col=lane&15, row=quad*4+reg
#pragma unroll
    for (int mt = 0; mt < MT; ++mt)
#pragma unroll
        for (int nt = 0; nt < 4; ++nt) {
            if (EPI == 0 && blockIdx.z == 2) {
                const int col  = n0 + wn * 64 + nt * 16 + l16;
                const int h    = (col >> 6) & 15;
                const int d    = col & 63;
                const int rowb = m0 + wm * (MT * 16) + mt * 16 + quad * 4;
                const int b    = rowb >> 11;
                const int s    = rowb & 2047;
                ushort4 o;   // V stored as FP16 for the f16 PV MFMA
                o.x = f2h(acc[mt][nt][0]);
                o.y = f2h(acc[mt][nt][1]);
                o.z = f2h(acc[mt][nt][2]);
                o.w = f2h(acc[mt][nt][3]);
                *(ushort4*)&Cp[((size_t)(b * 16 + h) * 64 + d) * S_LEN + s] = o;
            } else {
#pragma unroll
                for (int r = 0; r < 4; ++r) {
                    const int row = m0 + wm * (MT * 16) + mt * 16 + quad * 4 + r;
                    const int col = n0 + wn * 64 + nt * 16 + l16;
                    if (EPI == 2)
                        Cf[(size_t)row * N + col] = acc[mt][nt][r];
                    else
                        Cp[(size_t)row * N + col] = f2bf(acc[mt][nt][r] * cscale);
                }
            }
        }
}

// ---------------------------------------------------------------------------
// Attention v5: block = (bh, 128-q-tile), 4 waves each owning 32 q-rows and
// iterating the full j range in 128-tiles.
//  * K/V staged to LDS via global_load_lds (coalesced, no VGPR round-trip)
//    in an XOR-swizzled layout (slot = piece ^ (row & 7|15)) that is both
//    compatible with the wave-uniform-base+lane*16 DMA constraint and
//    conflict-free for the ds_read_b128 fragment reads.
//  * Double-buffered, ONE barrier per iter; the prefetch for tile t+1 is
//    issued immediately AFTER the barrier, so the compiler's vmcnt(0) drain
//    at the NEXT barrier waits on loads issued a full compute-phase earlier.
//  * Unstabilized exp2 softmax (scale folded into Q), cvt_pkrtz fp16 P,
//    f16 PV MFMA, li reduced once in the epilogue.
// Grid x = bh so XCD round-robin keeps each head's K/VT in one XCD's L2.
// ---------------------------------------------------------------------------
__global__ __launch_bounds__(256, 2)
void attn5(const u16* __restrict__ Qg, const u16* __restrict__ Kg,
           const u16* __restrict__ VTg /*fp16*/, const float* __restrict__ qp,
           u16* __restrict__ Mg) {
    const int tid  = threadIdx.x;
    const int lane = tid & 63;
    const int w    = tid >> 6;
    const int l32  = lane & 31;
    const int hi   = lane >> 5;
    const int bh   = blockIdx.x;
    const int b    = bh >> 4;
    const int h    = bh & 15;
    const int q0   = blockIdx.y * 128;

    // [buf][row][slot*8] ; K: 128 rows x 64 u16 (bf16), V: 64 rows x 128 u16 (fp16)
    __shared__ u16 lK[2][128 * 64];
    __shared__ u16 lV[2][64 * 128];

    const float qc = cosf(qp[0] + qp[1]);

    // Q as MFMA B-operand: lane = m = q0 + w*32 + l32, k = kk*16 + hi*8 + i
    short8 bq[4];
    {
        const u16* qrow = Qg + (size_t)(b * S_LEN + q0 + w * 32 + l32) * EDIM +
                          h * DK + hi * 8;
#pragma unroll
        for (int kk = 0; kk < 4; ++kk)
            bq[kk] = *(const short8*)(qrow + kk * 16);
    }

    // Staging lane->source mapping (swizzle): K piece pK = (lane&7)^((lane>>3)&7)
    const int kpiece = (lane & 7) ^ ((lane >> 3) & 7);
    const u16* kgbase = Kg + (size_t)b * S_LEN * EDIM + h * DK + kpiece * 8 +
                        (size_t)(w * 32 + (lane >> 3)) * EDIM;
    // V piece pV = (lane&15) ^ ((w*16 + i*4 + (lane>>4)) & 15)
    const u16* vgbase = VTg + (size_t)(bh * DK + w * 16 + (lane >> 4)) * S_LEN;

    f32x16 oacc[2] = {};   // lane = d = dt*32+l32, regs = m (C layout)
    float  li = 0.f;

    // ---- stage tile 0 into buf 0
#define STAGE(BUF, J0)                                                         \
    {                                                                          \
        _Pragma("unroll")                                                      \
        for (int i = 0; i < 4; ++i)                                            \
            ASYNC16(kgbase + (size_t)(J0 + i * 8) * EDIM,                      \
                    &lK[BUF][(w * 32 + i * 8) * 64]);                          \
        _Pragma("unroll")                                                      \
        for (int i = 0; i < 4; ++i) {                                          \
            const int pv = (lane & 15) ^ ((w * 16 + i * 4 + (lane >> 4)) & 15);\
            ASYNC16(vgbase + (size_t)(i * 4) * S_LEN + (J0) + pv * 8,          \
                    &lV[BUF][(w * 16 + i * 4) * 128]);                         \
        }                                                                      \
    }

    STAGE(0, 0)

    for (int t = 0; t < S_LEN / 128; ++t) {
        __syncthreads();                 // drains tile t's staging (issued 1 compute-phase ago)
        if (t + 1 < S_LEN / 128)
            STAGE((t + 1) & 1, (t + 1) * 128)
        const u16* bK = lK[t & 1];
        const u16* bVb = lV[t & 1];

#pragma unroll
        for (int jt = 0; jt < 4; ++jt) {
            // S^T tile: D[j][m], lane = m, regs = j
            const int jr = jt * 32 + l32;
            f32x16 sT = {};
#pragma unroll
            for (int kk = 0; kk < 4; ++kk) {
                const short8 aK = *(const short8*)
                    &bK[jr * 64 + ((kk * 2 + hi) ^ (l32 & 7)) * 8];
                sT = __builtin_amdgcn_mfma_f32_32x32x16_bf16(aK, bq[kk], sT, 0, 0, 0);
            }
            float e[16];
#pragma unroll
            for (int r = 0; r < 16; ++r) {
                e[r] = __builtin_amdgcn_exp2f(sT[r]);
                li += e[r];
            }
#pragma unroll
            for (int s = 0; s < 2; ++s) {
                const u32 P0 = __builtin_bit_cast(u32,
                    __builtin_amdgcn_cvt_pkrtz(e[8 * s + 0], e[8 * s + 1]));
                const u32 P1 = __builtin_bit_cast(u32,
                    __builtin_amdgcn_cvt_pkrtz(e[8 * s + 2], e[8 * s + 3]));
                const u32 P2 = __builtin_bit_cast(u32,
                    __builtin_amdgcn_cvt_pkrtz(e[8 * s + 4], e[8 * s + 5]));
                const u32 P3 = __builtin_bit_cast(u32,
                    __builtin_amdgcn_cvt_pkrtz(e[8 * s + 6], e[8 * s + 7]));
                const u32 XA = (u32)__shfl_xor((int)(hi ? P0 : P2), 32, 64);
                const u32 XB = (u32)__shfl_xor((int)(hi ? P1 : P3), 32, 64);
                u32x4 tt;
                tt[0] = hi ? XA : P0;
                tt[1] = hi ? XB : P1;
                tt[2] = hi ? P2 : XA;
                tt[3] = hi ? P3 : XB;
                const half8 aP = __builtin_bit_cast(half8, tt);
                const int ks = jt * 2 + s;
#pragma unroll
                for (int dt = 0; dt < 2; ++dt) {
                    const int d = dt * 32 + l32;
                    const half8 bV = *(const half8*)
                        &bVb[d * 128 + ((ks * 2 + hi) ^ (l32 & 15)) * 8];
                    oacc[dt] = __builtin_amdgcn_mfma_f32_32x32x16_f16(
                        aP, bV, oacc[dt], 0, 0, 0);
                }
            }
        }
    }
#undef STAGE

    // epilogue: li (lane = m) -> merge hi halves; normalize oacc (regs = m)
    li += __shfl_xor(li, 32, 64);
    const float inv = 1.f / li;
#pragma unroll
    for (int r = 0; r < 16; ++r) {
        const int ml   = (r & 3) + 8 * (r >> 2) + 4 * hi;
        const float im = __shfl(inv, ml, 64);
        const int sg   = q0 + w * 32 + ml;
#pragma unroll
        for (int dt = 0; dt < 2; ++dt) {
            const int d = dt * 32 + l32;
            float val = oacc[dt][r] * im;
            if (d < 4) val += qc;
            Mg[(size_t)(b * S_LEN + sg) * EDIM + h * DK + d] = f2bf(val);
        }
    }
}

// ---------------------------------------------------------------------------
// Workspace: fast path (ws >= 22 MB): xb[0,8M) + VT[8M,16M) + Wqkv[16M,22M);
//   Wo converted into the Wq slot after the QKV GEMM (stream-ordered).
// tight path (ws >= 16 MB): xb + VT only; weights read fp32 inside the GEMM.
// Q,K (bf16, 8 MB each) live in d_out (16 MB fp32), dead before the final
// projection overwrites it.  Host branch depends only on ws_size (constant).
// ---------------------------------------------------------------------------
extern "C" void kernel_launch(void* const* d_in, const int* in_sizes, int n_in,
                              void* d_out, int out_size, void* d_ws, size_t ws_size,
                              hipStream_t stream) {
    const float* x  = (const float*)d_in[0];
    const float* Wq = (const float*)d_in[1];
    const float* Wk = (const float*)d_in[2];
    const float* Wv = (const float*)d_in[3];
    const float* Wo = (const float*)d_in[4];
    const float* qp = (const float*)d_in[5];

    const size_t BUF  = (size_t)2 * S_LEN * EDIM;   // 4M elements
    const size_t WBUF = (size_t)EDIM * EDIM;        // 1M elements

    u16* Q  = (u16*)d_out;
    u16* Kb = Q + BUF;

    u16* ws    = (u16*)d_ws;
    u16* xb    = ws;                 // dead after QKV; mixed reuses it
    u16* mixed = xb;
    u16* VT    = ws + BUF;           // fp16 V^T
    u16* Wqb   = ws + 2 * BUF;       // fast path only: Wq,Wk,Wv contiguous
    u16* Wkb   = Wqb + WBUF;
    u16* Wvb   = Wkb + WBUF;
    u16* Wob   = Wqb;                // reuses Wq slot after QKV GEMM
    float* out = (float*)d_out;

    const int M = 2 * S_LEN, N = EDIM, Kd = EDIM;
    const dim3 gqkv(N / 128, M / 128, 3);
    const dim3 gfin(N / 128, M / 64, 1);            // 64-row tiles: 512 blocks
    const dim3 gattn(2 * NHEAD, S_LEN / 128, 1);    // x = bh for XCD locality
    const bool fast = ws_size >= (size_t)(2 * BUF + 3 * WBUF) * sizeof(u16);

    if (fast) {
        conv_all<<<7168, 256, 0, stream>>>(x, Wq, Wk, Wv, xb, Wqb);
        gemm128<0, false, 4><<<gqkv, 256, 0, stream>>>(
            xb, Wqb, Wkb, Wvb, Q, Kb, VT, nullptr, M, N, Kd);
        f32_to_bf16<<<(int)(WBUF / 1024), 256, 0, stream>>>(Wo, Wob, (int)WBUF);
        attn5<<<gattn, 256, 0, stream>>>(Q, Kb, VT, qp, mixed);
        gemm128<2, false, 2><<<gfin, 256, 0, stream>>>(
            mixed, Wob, Wob, Wob, nullptr, nullptr, nullptr, out, M, N, Kd);
    } else {
        f32_to_bf16<<<(int)(BUF / 1024), 256, 0, stream>>>(x, xb, (int)BUF);
        gemm128<0, true, 4><<<gqkv, 256, 0, stream>>>(
            xb, Wq, Wk, Wv, Q, Kb, VT, nullptr, M, N, Kd);
        attn5<<<gattn, 256, 0, stream>>>(Q, Kb, VT, qp, mixed);
        gemm128<2, true, 2><<<gfin, 256, 0, stream>>>(
            mixed, Wo, Wo, Wo, nullptr, nullptr, nullptr, out, M, N, Kd);
    }
}

// Round 9
// 170.235 us; speedup vs baseline: 1.5231x; 1.1006x over previous
//
#include <hip/hip_runtime.h>

typedef unsigned short u16;
typedef unsigned int u32;
typedef __attribute__((ext_vector_type(8))) short short8;
typedef __attribute__((ext_vector_type(8))) _Float16 half8;
typedef __attribute__((ext_vector_type(4))) float f32x4;
typedef __attribute__((ext_vector_type(16))) float f32x16;
typedef __attribute__((ext_vector_type(4))) u32 u32x4;

#define S_LEN 2048
#define EDIM  1024
#define DK    64
#define NHEAD 16
// softmax scale 1/8 folded with log2(e) into the Q projection:
#define QSCALE 0.1803368801111f

__device__ inline u16 f2bf(float f) {
    u32 u = __builtin_bit_cast(u32, f);
    u += 0x7fffu + ((u >> 16) & 1u);   // RNE
    return (u16)(u >> 16);
}
__device__ inline u16 f2h(float f) {   // fp32 -> fp16 bits (RNE)
    _Float16 h = (_Float16)f;
    return __builtin_bit_cast(u16, h);
}

#define ASYNC16(gp, lp)                                                        \
    __builtin_amdgcn_global_load_lds(                                          \
        (const __attribute__((address_space(1))) u32*)(gp),                    \
        (__attribute__((address_space(3))) u32*)(lp), 16, 0, 0)

// ---------------------------------------------------------------------------
// Fused fp32->bf16 converts: segment 0 = x (4M els), 1..3 = Wq/Wk/Wv (1M each)
// ---------------------------------------------------------------------------
__global__ __launch_bounds__(256)
void conv_all(const float* __restrict__ x,  const float* __restrict__ Wq,
              const float* __restrict__ Wk, const float* __restrict__ Wv,
              u16* __restrict__ xb, u16* __restrict__ Wb /*3M contiguous*/) {
    const int blk = blockIdx.x;
    const float* src; u16* dst; int idx;
    if (blk < 4096)      { src = x;  dst = xb;             idx = blk; }
    else if (blk < 5120) { src = Wq; dst = Wb;             idx = blk - 4096; }
    else if (blk < 6144) { src = Wk; dst = Wb + (1 << 20); idx = blk - 5120; }
    else                 { src = Wv; dst = Wb + (2 << 20); idx = blk - 6144; }
    const int i = idx * 1024 + threadIdx.x * 4;
    const float4 v = *(const float4*)(src + i);
    u16 o[4] = { f2bf(v.x), f2bf(v.y), f2bf(v.z), f2bf(v.w) };
    *(ulong1*)(dst + i) = *(ulong1*)o;
}

__global__ __launch_bounds__(256)
void f32_to_bf16(const float* __restrict__ src, u16* __restrict__ dst, int n) {
    const int i = (blockIdx.x * 256 + threadIdx.x) * 4;
    if (i + 3 < n) {
        const float4 v = *(const float4*)(src + i);
        u16 o[4] = { f2bf(v.x), f2bf(v.y), f2bf(v.z), f2bf(v.w) };
        *(ulong1*)(dst + i) = *(ulong1*)o;
    }
}

// ---------------------------------------------------------------------------
// NT GEMM: C[m][n] = sum_k A[m][k]*B[n][k]. Block tile (MT*32) x 128.
// bf16 path: BK=64, XOR-swizzled LDS (slot = piece ^ (row&7)) so the 128B
// row stride stays conflict-free for ds_read_b128 while global_load_lds
// staging reads coalesced 128B segments. Halves barrier count vs BK=32.
// EPI 0 (QKV fused, z selects): z0 -> Q bf16 * QSCALE, z1 -> K bf16,
//   z2 -> V scattered to VT as FP16 with the sigma(j) permutation (swap j
//   bits 2,3 within each 16-group = swap the quad bits) so attention's PV
//   MFMA can consume P in C/D register order with NO cross-lane exchange.
// EPI 2: fp32 row-major.
// BF32 (tight-ws fallback): legacy BK=32 path, B fp32 staged + converted.
// ---------------------------------------------------------------------------
template<int EPI, bool BF32, int MT>
__global__ __launch_bounds__(256, 2)
void gemm128(const u16* __restrict__ A,
             const void* __restrict__ B0, const void* __restrict__ B1,
             const void* __restrict__ B2,
             u16* __restrict__ C0, u16* __restrict__ C1, u16* __restrict__ C2,
             float* __restrict__ Cf, int M, int N, int K) {
    const void* Bv = B0;
    u16*        Cp = C0;
    float       cscale = (EPI == 0) ? QSCALE : 1.0f;
    if (blockIdx.z == 1) { Bv = B1; Cp = C1; cscale = 1.0f; }
    else if (blockIdx.z == 2) { Bv = B2; Cp = C2; cscale = 1.0f; }

    const int tid  = threadIdx.x;
    const int lane = tid & 63;
    const int w    = tid >> 6;
    const int quad = lane >> 4;
    const int l16  = lane & 15;
    const int wm   = w >> 1;
    const int wn   = w & 1;
    const int m0   = blockIdx.y * (MT * 32);
    const int n0   = blockIdx.x * 128;

    __shared__ u16 lA[MT * 32 * (BF32 ? 32 : 64)];
    __shared__ __align__(16) char lBraw[BF32 ? 128 * 32 * 4 : 128 * 64 * 2];

    f32x4 acc[MT][4] = {};

    if (!BF32) {
        // ---- BK = 64, swizzled ----
        u16* lB = (u16*)lBraw;
        const int rsub  = lane >> 3;           // 0..7
        const int piece = (lane & 7) ^ (rsub & 7);
        for (int k0 = 0; k0 < K; k0 += 64) {
            __syncthreads();
#pragma unroll
            for (int i = 0; i < MT; ++i) {
                const int row = w * (MT * 8) + i * 8 + rsub;
                ASYNC16(A + (size_t)(m0 + row) * K + k0 + piece * 8,
                        &lA[(w * (MT * 8) + i * 8) * 64]);
            }
            const u16* Bp = (const u16*)Bv;
#pragma unroll
            for (int i = 0; i < 4; ++i) {
                const int row = w * 32 + i * 8 + rsub;
                ASYNC16(Bp + (size_t)(n0 + row) * K + k0 + piece * 8,
                        &lB[(w * 32 + i * 8) * 64]);
            }
            __syncthreads();

#pragma unroll
            for (int ks = 0; ks < 2; ++ks) {
                short8 av[MT], bv[4];
#pragma unroll
                for (int t = 0; t < MT; ++t)
                    av[t] = *(const short8*)&lA[(wm * (MT * 16) + t * 16 + l16) * 64 +
                                                (((ks * 4 + quad)) ^ (l16 & 7)) * 8];
#pragma unroll
                for (int t = 0; t < 4; ++t)
                    bv[t] = *(const short8*)&lB[(wn * 64 + t * 16 + l16) * 64 +
                                                (((ks * 4 + quad)) ^ (l16 & 7)) * 8];
#pragma unroll
                for (int mt = 0; mt < MT; ++mt)
#pragma unroll
                    for (int nt = 0; nt < 4; ++nt)
                        acc[mt][nt] = __builtin_amdgcn_mfma_f32_16x16x32_bf16(
                            av[mt], bv[nt], acc[mt][nt], 0, 0, 0);
            }
        }
    } else {
        // ---- legacy BK = 32, B fp32 ----
        for (int k0 = 0; k0 < K; k0 += 32) {
            __syncthreads();
#pragma unroll
            for (int i = 0; i < MT / 2; ++i) {
                const int row = w * (MT * 8) + i * 16 + (lane >> 2);
                const int col = (lane & 3) * 8;
                ASYNC16(A + (size_t)(m0 + row) * K + k0 + col,
                        &lA[(w * (MT * 8) + i * 16) * 32]);
            }
            const float* Bp  = (const float*)Bv;
            float*       lBs = (float*)lBraw;
#pragma unroll
            for (int i = 0; i < 4; ++i) {
                const int row = w * 32 + i * 8 + (lane >> 3);
                const int col = (lane & 7) * 4;
                ASYNC16(Bp + (size_t)(n0 + row) * K + k0 + col,
                        &lBs[(w * 32 + i * 8) * 32]);
            }
            __syncthreads();

            short8 av[MT], bv[4];
#pragma unroll
            for (int t = 0; t < MT; ++t)
                av[t] = *(const short8*)&lA[(wm * (MT * 16) + t * 16 + l16) * 32 + quad * 8];
            const float* lBr = (const float*)lBraw;
#pragma unroll
            for (int t = 0; t < 4; ++t) {
                const float* src = &lBr[(wn * 64 + t * 16 + l16) * 32 + quad * 8];
                const f32x4 x0 = *(const f32x4*)src;
                const f32x4 x1 = *(const f32x4*)(src + 4);
                short8 bq;
#pragma unroll
                for (int j = 0; j < 4; ++j) {
                    bq[j]     = (short)f2bf(x0[j]);
                    bq[4 + j] = (short)f2bf(x1[j]);
                }
                bv[t] = bq;
            }
#pragma unroll
            for (int mt = 0; mt < MT; ++mt)
#pragma unroll
                for (int nt = 0; nt < 4; ++nt)
                    acc[mt][nt] = __builtin_amdgcn_mfma_f32_16x16x32_bf16(
                        av[mt], bv[nt], acc[mt][nt], 0, 0, 0);
        }
    }

    // epilogue: C/D layout col=lane&15, row=quad*4+reg
#pragma unroll
    for (int mt = 0; mt < MT; ++mt)
#pragma unroll
        for (int nt = 0; nt < 4; ++nt) {
            if (EPI == 0 && blockIdx.z == 2) {
                // V -> VT[(b*16+h)*64+d][sigma(s)] as fp16.
                // sigma swaps j bits 2,3 within a 16-group == swap quad bits.
                const int col    = n0 + wn * 64 + nt * 16 + l16;
                const int h      = (col >> 6) & 15;
                const int d      = col & 63;
                const int quadsw = ((quad & 1) << 1) | (quad >> 1);
                const int rowb   = m0 + wm * (MT * 16) + mt * 16;  // 16-aligned
                const int b      = rowb >> 11;
                const int s      = (rowb & 2047) + quadsw * 4;
                ushort4 o;
                o.x = f2h(acc[mt][nt][0]);
                o.y = f2h(acc[mt][nt][1]);
                o.z = f2h(acc[mt][nt][2]);
                o.w = f2h(acc[mt][nt][3]);
                *(ushort4*)&Cp[((size_t)(b * 16 + h) * 64 + d) * S_LEN + s] = o;
            } else {
#pragma unroll
                for (int r = 0; r < 4; ++r) {
                    const int row = m0 + wm * (MT * 16) + mt * 16 + quad * 4 + r;
                    const int col = n0 + wn * 64 + nt * 16 + l16;
                    if (EPI == 2)
                        Cf[(size_t)row * N + col] = acc[mt][nt][r];
                    else
                        Cp[(size_t)row * N + col] = f2bf(acc[mt][nt][r] * cscale);
                }
            }
        }
}

// ---------------------------------------------------------------------------
// Attention v6: attn5 structure (128-q block, 128-j LDS tiles via
// global_load_lds, double-buffered, one barrier/iter, post-barrier prefetch)
// with the P-operand exchange ELIMINATED: VT is stored sigma-permuted by the
// V-epilogue, so aP = {P0,P1,P2,P3} feeds the f16 PV MFMA directly.
// Chain-breaking: separate oacc per s-group, 4-way li accumulators.
// Grid x = bh so XCD round-robin keeps each head's K/VT in one XCD's L2.
// ---------------------------------------------------------------------------
__global__ __launch_bounds__(256, 2)
void attn6(const u16* __restrict__ Qg, const u16* __restrict__ Kg,
           const u16* __restrict__ VTg /*fp16, sigma-permuted*/,
           const float* __restrict__ qp, u16* __restrict__ Mg) {
    const int tid  = threadIdx.x;
    const int lane = tid & 63;
    const int w    = tid >> 6;
    const int l32  = lane & 31;
    const int hi   = lane >> 5;
    const int bh   = blockIdx.x;
    const int b    = bh >> 4;
    const int h    = bh & 15;
    const int q0   = blockIdx.y * 128;

    __shared__ u16 lK[2][128 * 64];   // [buf][row j][slot*8] bf16, swizzled
    __shared__ u16 lV[2][64 * 128];   // [buf][row d][slot*8] fp16, swizzled

    const float qc = cosf(qp[0] + qp[1]);

    // Q as MFMA B-operand: lane = m = q0 + w*32 + l32, k = kk*16 + hi*8 + i
    short8 bq[4];
    {
        const u16* qrow = Qg + (size_t)(b * S_LEN + q0 + w * 32 + l32) * EDIM +
                          h * DK + hi * 8;
#pragma unroll
        for (int kk = 0; kk < 4; ++kk)
            bq[kk] = *(const short8*)(qrow + kk * 16);
    }

    const int kpiece = (lane & 7) ^ ((lane >> 3) & 7);
    const u16* kgbase = Kg + (size_t)b * S_LEN * EDIM + h * DK + kpiece * 8 +
                        (size_t)(w * 32 + (lane >> 3)) * EDIM;
    const u16* vgbase = VTg + (size_t)(bh * DK + w * 16 + (lane >> 4)) * S_LEN;

    f32x16 oacc[2][2] = {};   // [s-group][dt]; lane = d, regs = m (C layout)
    float  la[4] = {};        // li partial chains

#define STAGE(BUF, J0)                                                         \
    {                                                                          \
        _Pragma("unroll")                                                      \
        for (int i = 0; i < 4; ++i)                                            \
            ASYNC16(kgbase + (size_t)(J0 + i * 8) * EDIM,                      \
                    &lK[BUF][(w * 32 + i * 8) * 64]);                          \
        _Pragma("unroll")                                                      \
        for (int i = 0; i < 4; ++i) {                                          \
            const int pv = (lane & 15) ^ ((w * 16 + i * 4 + (lane >> 4)) & 15);\
            ASYNC16(vgbase + (size_t)(i * 4) * S_LEN + (J0) + pv * 8,          \
                    &lV[BUF][(w * 16 + i * 4) * 128]);                         \
        }                                                                      \
    }

    STAGE(0, 0)

    for (int t = 0; t < S_LEN / 128; ++t) {
        __syncthreads();   // drains tile t's staging (issued 1 compute-phase ago)
        if (t + 1 < S_LEN / 128)
            STAGE((t + 1) & 1, (t + 1) * 128)
        const u16* bK  = lK[t & 1];
        const u16* bVb = lV[t & 1];

#pragma unroll
        for (int jt = 0; jt < 4; ++jt) {
            const int jr = jt * 32 + l32;
            f32x16 sT = {};
#pragma unroll
            for (int kk = 0; kk < 4; ++kk) {
                const short8 aK = *(const short8*)
                    &bK[jr * 64 + ((kk * 2 + hi) ^ (l32 & 7)) * 8];
                sT = __builtin_amdgcn_mfma_f32_32x32x16_bf16(aK, bq[kk], sT, 0, 0, 0);
            }
            float e[16];
#pragma unroll
            for (int r = 0; r < 16; ++r) {
                e[r] = __builtin_amdgcn_exp2f(sT[r]);
                la[r & 3] += e[r];
            }
#pragma unroll
            for (int s = 0; s < 2; ++s) {
                u32x4 tt;
                tt[0] = __builtin_bit_cast(u32,
                    __builtin_amdgcn_cvt_pkrtz(e[8 * s + 0], e[8 * s + 1]));
                tt[1] = __builtin_bit_cast(u32,
                    __builtin_amdgcn_cvt_pkrtz(e[8 * s + 2], e[8 * s + 3]));
                tt[2] = __builtin_bit_cast(u32,
                    __builtin_amdgcn_cvt_pkrtz(e[8 * s + 4], e[8 * s + 5]));
                tt[3] = __builtin_bit_cast(u32,
                    __builtin_amdgcn_cvt_pkrtz(e[8 * s + 6], e[8 * s + 7]));
                const half8 aP = __builtin_bit_cast(half8, tt);
                const int ks = jt * 2 + s;
#pragma unroll
                for (int dt = 0; dt < 2; ++dt) {
                    const int d = dt * 32 + l32;
                    const half8 bV = *(const half8*)
                        &bVb[d * 128 + ((ks * 2 + hi) ^ (l32 & 15)) * 8];
                    oacc[s][dt] = __builtin_amdgcn_mfma_f32_32x32x16_f16(
                        aP, bV, oacc[s][dt], 0, 0, 0);
                }
            }
        }
    }
#undef STAGE

    // epilogue: li (lane = m) -> merge hi halves; normalize (regs = m)
    float li = (la[0] + la[1]) + (la[2] + la[3]);
    li += __shfl_xor(li, 32, 64);
    const float inv = 1.f / li;
#pragma unroll
    for (int r = 0; r < 16; ++r) {
        const int ml   = (r & 3) + 8 * (r >> 2) + 4 * hi;
        const float im = __shfl(inv, ml, 64);
        const int sg   = q0 + w * 32 + ml;
#pragma unroll
        for (int dt = 0; dt < 2; ++dt) {
            const int d = dt * 32 + l32;
            float val = (oacc[0][dt][r] + oacc[1][dt][r]) * im;
            if (d < 4) val += qc;
            Mg[(size_t)(b * S_LEN + sg) * EDIM + h * DK + d] = f2bf(val);
        }
    }
}

// ---------------------------------------------------------------------------
// Workspace: fast path (ws >= 22 MB): xb[0,8M) + VT[8M,16M) + Wqkv[16M,22M);
//   Wo converted into the Wq slot after the QKV GEMM (stream-ordered).
// tight path (ws >= 16 MB): xb + VT only; weights read fp32 inside the GEMM.
// Q,K (bf16, 8 MB each) live in d_out (16 MB fp32), dead before the final
// projection overwrites it.  Host branch depends only on ws_size (constant).
// ---------------------------------------------------------------------------
extern "C" void kernel_launch(void* const* d_in, const int* in_sizes, int n_in,
                              void* d_out, int out_size, void* d_ws, size_t ws_size,
                              hipStream_t stream) {
    const float* x  = (const float*)d_in[0];
    const float* Wq = (const float*)d_in[1];
    const float* Wk = (const float*)d_in[2];
    const float* Wv = (const float*)d_in[3];
    const float* Wo = (const float*)d_in[4];
    const float* qp = (const float*)d_in[5];

    const size_t BUF  = (size_t)2 * S_LEN * EDIM;   // 4M elements
    const size_t WBUF = (size_t)EDIM * EDIM;        // 1M elements

    u16* Q  = (u16*)d_out;
    u16* Kb = Q + BUF;

    u16* ws    = (u16*)d_ws;
    u16* xb    = ws;                 // dead after QKV; mixed reuses it
    u16* mixed = xb;
    u16* VT    = ws + BUF;           // fp16 V^T (sigma-permuted)
    u16* Wqb   = ws + 2 * BUF;       // fast path only: Wq,Wk,Wv contiguous
    u16* Wkb   = Wqb + WBUF;
    u16* Wvb   = Wkb + WBUF;
    u16* Wob   = Wqb;                // reuses Wq slot after QKV GEMM
    float* out = (float*)d_out;

    const int M = 2 * S_LEN, N = EDIM, Kd = EDIM;
    const dim3 gqkv(N / 128, M / 128, 3);
    const dim3 gfin(N / 128, M / 64, 1);            // 64-row tiles: 512 blocks
    const dim3 gattn(2 * NHEAD, S_LEN / 128, 1);    // x = bh for XCD locality
    const bool fast = ws_size >= (size_t)(2 * BUF + 3 * WBUF) * sizeof(u16);

    if (fast) {
        conv_all<<<7168, 256, 0, stream>>>(x, Wq, Wk, Wv, xb, Wqb);
        gemm128<0, false, 4><<<gqkv, 256, 0, stream>>>(
            xb, Wqb, Wkb, Wvb, Q, Kb, VT, nullptr, M, N, Kd);
        f32_to_bf16<<<(int)(WBUF / 1024), 256, 0, stream>>>(Wo, Wob, (int)WBUF);
        attn6<<<gattn, 256, 0, stream>>>(Q, Kb, VT, qp, mixed);
        gemm128<2, false, 2><<<gfin, 256, 0, stream>>>(
            mixed, Wob, Wob, Wob, nullptr, nullptr, nullptr, out, M, N, Kd);
    } else {
        f32_to_bf16<<<(int)(BUF / 1024), 256, 0, stream>>>(x, xb, (int)BUF);
        gemm128<0, true, 4><<<gqkv, 256, 0, stream>>>(
            xb, Wq, Wk, Wv, Q, Kb, VT, nullptr, M, N, Kd);
        attn6<<<gattn, 256, 0, stream>>>(Q, Kb, VT, qp, mixed);
        gemm128<2, true, 2><<<gfin, 256, 0, stream>>>(
            mixed, Wo, Wo, Wo, nullptr, nullptr, nullptr, out, M, N, Kd);
    }
}